// Round 4
// baseline (259.619 us; speedup 1.0000x reference)
//
#include <hip/hip_runtime.h>

typedef _Float16 f16;
typedef _Float16 f16x8 __attribute__((ext_vector_type(8)));
typedef _Float16 f16x4 __attribute__((ext_vector_type(4)));
typedef float f32x4 __attribute__((ext_vector_type(4)));

#define MFMA16(a, b, c) __builtin_amdgcn_mfma_f32_16x16x32_f16((a), (b), (c), 0, 0, 0)
// compiler-only fence: pins LDS op order across TBAA-distinct vector types
#define MEMBAR() __asm__ __volatile__("" ::: "memory")

// async global->LDS, 16B per lane. lds dest = wave-uniform base + lane*16.
__device__ __forceinline__ void cp16(const f16* g, f16* l) {
  __builtin_amdgcn_global_load_lds(
      (const __attribute__((address_space(1))) void*)g,
      (__attribute__((address_space(3))) void*)l, 16, 0, 0);
}

// ---------------- fp32 -> fp16 convert, all 5 tensors in one launch ----------------
__global__ __launch_bounds__(256) void cvt_all(
    const float* __restrict__ x,  const float* __restrict__ Wq,
    const float* __restrict__ Wk, const float* __restrict__ Wv,
    const float* __restrict__ Wo,
    f16* __restrict__ X16, f16* __restrict__ Wq16, f16* __restrict__ Wk16,
    f16* __restrict__ Wv16, f16* __restrict__ Wo16) {
  int blk = blockIdx.x;
  const float* src; f16* dst; size_t off;
  if (blk < 4096) { src = x; dst = X16; off = (size_t)blk * 2048; }
  else {
    int t = blk - 4096, widx = t >> 9, loc = t & 511;
    src = (widx == 0) ? Wq : (widx == 1) ? Wk : (widx == 2) ? Wv : Wo;
    dst = (widx == 0) ? Wq16 : (widx == 1) ? Wk16 : (widx == 2) ? Wv16 : Wo16;
    off = (size_t)loc * 2048;
  }
  size_t e = off + (size_t)threadIdx.x * 8;
  const float4* s = (const float4*)(src + e);
  float4 a = s[0], b = s[1];
  f16x8 o;
  o[0] = (f16)a.x; o[1] = (f16)a.y; o[2] = (f16)a.z; o[3] = (f16)a.w;
  o[4] = (f16)b.x; o[5] = (f16)b.y; o[6] = (f16)b.z; o[7] = (f16)b.w;
  *(f16x8*)(dst + e) = o;
}

// ---------------- pipelined GEMM core: C[M,N] = scale * A[M,K] * B[N,K]^T ----------------
// BM=BN=128, BK=32, double-buffered (32 KB LDS -> 4 blocks/CU). Per iter each
// wave prefetches tile i+1 (4 cp16, FIFO A0,A1,B0,B1), waits vmcnt(4) (tile i),
// raw s_barrier, 8 ds_read_b128 + 16 MFMA, barrier. BK=32 swizzle: logical
// chunk q of row r stored at position q^((r>>1)&3) -> 8 lanes/bank-group (min).
// permT: permute low-6 column bits [b5 b4 b3 b2 b1 b0]->[b5 b3 b2 b4 b1 b0]
// (bakes attn's PV k-axis permutation into the global VT layout).
__device__ __forceinline__ void gemm_core(
    const f16* __restrict__ A, const f16* __restrict__ B, void* __restrict__ Cv,
    bool outF16, bool permT, int N, int K, int bm, int bn, float scale,
    f16* As, f16* Bs) {
  const int tid = threadIdx.x;
  const int lane = tid & 63, w = tid >> 6;
  const int wm = w >> 1, wn = w & 1;
  const int c = lane & 15, q = lane >> 4;
  const int key = (c >> 1) & 3;  // read-side swizzle key
  f32x4 acc[4][4] = {};

  // stage one BK=32 tile into buffer bufi: per wave 2 windows x (A,B)
  const int Lrow = lane >> 2, Lp = (lane & 3) ^ ((lane >> 3) & 3);
  auto stage = [&](int k0, int bufi) {
#pragma unroll
    for (int j = 0; j < 2; ++j) {
      int r0 = (w * 2 + j) * 16;
      cp16(A + (size_t)(bm + r0 + Lrow) * K + k0 + Lp * 8,
           As + bufi * 4096 + r0 * 32 + lane * 8);
    }
#pragma unroll
    for (int j = 0; j < 2; ++j) {
      int r0 = (w * 2 + j) * 16;
      cp16(B + (size_t)(bn + r0 + Lrow) * K + k0 + Lp * 8,
           Bs + bufi * 4096 + r0 * 32 + lane * 8);
    }
  };

  stage(0, 0);
  const int NIT = K >> 5;
  for (int i = 0; i < NIT; ++i) {
    if (i + 1 < NIT) {
      stage((i + 1) << 5, (i + 1) & 1);     // prefetch, stays in flight
      __builtin_amdgcn_s_waitcnt(0x0F74);   // vmcnt(4): tile i's loads only
    } else {
      __builtin_amdgcn_s_waitcnt(0x0F70);   // vmcnt(0)
    }
    __builtin_amdgcn_s_barrier();
    MEMBAR();
    const f16* Ab = As + (i & 1) * 4096;
    const f16* Bb = Bs + (i & 1) * 4096;
    f16x8 af[4], bf[4];
#pragma unroll
    for (int mt = 0; mt < 4; ++mt)
      af[mt] = *(const f16x8*)(Ab + (wm * 64 + mt * 16 + c) * 32 + (q ^ key) * 8);
#pragma unroll
    for (int nt = 0; nt < 4; ++nt)
      bf[nt] = *(const f16x8*)(Bb + (wn * 64 + nt * 16 + c) * 32 + (q ^ key) * 8);
#pragma unroll
    for (int mt = 0; mt < 4; ++mt)
#pragma unroll
      for (int nt = 0; nt < 4; ++nt)
        acc[mt][nt] = MFMA16(af[mt], bf[nt], acc[mt][nt]);
    MEMBAR();
    __builtin_amdgcn_s_barrier();  // all waves done with buf i&1 before refill
  }

#pragma unroll
  for (int mt = 0; mt < 4; ++mt)
#pragma unroll
    for (int nt = 0; nt < 4; ++nt)
#pragma unroll
      for (int r = 0; r < 4; ++r) {
        size_t row = bm + wm * 64 + mt * 16 + q * 4 + r;  // C/D: row=(lane>>4)*4+reg
        size_t col = bn + wn * 64 + nt * 16 + c;          //      col=lane&15
        if (permT) {
          int t = (int)col & 63;
          col = (col & ~(size_t)63) |
                (size_t)((t & 0x23) | ((t & 0x0C) << 1) | ((t & 0x10) >> 2));
        }
        float v = acc[mt][nt][r] * scale;
        if (outF16) ((f16*)Cv)[row * N + col] = (f16)v;
        else ((float*)Cv)[row * N + col] = v;
      }
}

// fused Q/K/V^T projections: z=0 Q=X·Wq^T (scaled cs), z=1 K=X·Wk^T,
// z=2 V^T = Wv·X^T (M=1024, N=8192 -> dim-major, key-permuted for attn)
__global__ __launch_bounds__(256, 4) void gemm_qkvt(
    const f16* __restrict__ X, const f16* __restrict__ Wq,
    const f16* __restrict__ Wk, const f16* __restrict__ Wv,
    f16* __restrict__ Q, f16* __restrict__ Ko, f16* __restrict__ VT, float cs) {
  __shared__ __align__(16) f16 As[8192], Bs[8192];
  const int z = blockIdx.z, x = blockIdx.x;
  if (z < 2) {
    gemm_core(X, z ? Wk : Wq, z ? (void*)Ko : (void*)Q, true, false, 1024, 1024,
              (x >> 3) * 128, (x & 7) * 128, z ? 1.0f : cs, As, Bs);
  } else {
    gemm_core(Wv, X, (void*)VT, true, true, 8192, 1024,
              (x >> 6) * 128, (x & 63) * 128, 1.0f, As, Bs);
  }
}

// output projection: d_out(fp32) = A16 · Wo^T
__global__ __launch_bounds__(256, 4) void gemm_o(
    const f16* __restrict__ A, const f16* __restrict__ Wo, float* __restrict__ out) {
  __shared__ __align__(16) f16 As[8192], Bs[8192];
  const int x = blockIdx.x;
  gemm_core(A, Wo, (void*)out, false, false, 1024, 1024,
            (x >> 3) * 128, (x & 7) * 128, 1.0f, As, Bs);
}

// ---------------- flash attention (round-11: 4 q-groups/wave) ----------------
// 256-thr/4-wave blocks, each wave owns 64 q-rows (4 groups of 16) -> K/V
// LDS fragment reads amortized over 4 MFMAs (LDS-port pressure halved vs
// round-10's 2 groups). 64-key tile processed in two 32-key halves to cap
// live registers (st[2][4] = 32 regs, not 64) and give the compiler two
// independent QK->SM->PV chains to interleave. P stays in registers via the
// k-axis permutation (VT pre-permuted by gemm_qkvt permT).
// launch_bounds (256,2): ~256-reg cap, est. peak ~175 -> no spill
// (round-2 lesson: the spill tripwire is WRITE_SIZE >> 16 MB).
__global__ __launch_bounds__(256, 2) void attn_kernel(
    const f16* __restrict__ Qg, const f16* __restrict__ Kg,
    const f16* __restrict__ VTg, f16* __restrict__ Og) {
  const int T = 2048, D = 1024;
  const int x = blockIdx.x;                 // 512 blocks flattened
  const int xcd = x & 7, rem = x >> 3;
  const int qt = rem & 7, grp = rem >> 3;
  const int bh = (grp << 3) | xcd;          // XCD = bh&7 for all 8 qt
  const int b = bh >> 4, h = bh & 15;
  const size_t base = ((size_t)b * T) * D + h * 64;            // Q, K, O
  const size_t baseV = (size_t)h * 64 * 8192 + (size_t)b * T;  // VT[1024][8192]
  __shared__ __align__(16) f16 smem[16384];  // 32 KB: K dbuf 16K + V dbuf 16K
  const int tid = threadIdx.x;
  const int lane = tid & 63, w = tid >> 6;   // w in [0,4)
  const int c = lane & 15, q = lane >> 4;
  const int cx = c & 7;
  f16* Kb = smem;                     // [2][64*64] swizzled
  f16* Vb = smem + 8192;              // [2][64*64] swizzled (keys pre-permuted)

  // stage Q: 256 rows x 64 dims across the full 32KB of smem (8 cp16/wave)
#pragma unroll
  for (int j = 0; j < 8; ++j) {
    int cb = (w * 8 + j) * 64;
    int ch = cb + lane;
    int row = ch >> 3, p = (ch & 7) ^ (row & 7);
    cp16(Qg + base + (size_t)(qt * 256 + row) * D + p * 8, smem + cb * 8);
  }
  __syncthreads();
  f16x8 qf[4][2];  // Q^T B-fragments, persistent (rows w*64 .. w*64+63)
#pragma unroll
  for (int g = 0; g < 4; ++g)
#pragma unroll
    for (int kh = 0; kh < 2; ++kh)
      qf[g][kh] = *(const f16x8*)(smem + (w * 64 + g * 16 + c) * 64 + ((kh * 4 + q) ^ cx) * 8);
  __syncthreads();  // all qf reads done before DMA overwrites Q region

  float l_[4] = {0.f, 0.f, 0.f, 0.f};
  f32x4 o_[4][4] = {};

  // per wave: 2 K cp16 + 2 V cp16 cover the 64x64 tiles across 4 waves
  auto stageKV = [&](int kv, int bufi) {
    f16* Ks = Kb + bufi * 4096;
    f16* Vt = Vb + bufi * 4096;
#pragma unroll
    for (int j = 0; j < 2; ++j) {
      int cb = (w * 2 + j) * 64;
      int ch = cb + lane;
      int row = ch >> 3, p = (ch & 7) ^ (row & 7);
      cp16(Kg + base + (size_t)(kv + row) * D + p * 8, Ks + cb * 8);
    }
#pragma unroll
    for (int j = 0; j < 2; ++j) {
      int cb = (w * 2 + j) * 64;
      int ch = cb + lane;
      int row = ch >> 3, p = (ch & 7) ^ (row & 7);
      cp16(VTg + baseV + (size_t)row * 8192 + kv + p * 8, Vt + cb * 8);
    }
  };

  stageKV(0, 0);
  for (int i = 0; i < 32; ++i) {
    if (i < 31) {
      stageKV((i + 1) * 64, (i + 1) & 1);          // prefetch, stays in flight
      __builtin_amdgcn_s_waitcnt(0x0F74);          // vmcnt(4): tile i's 4 loads
    } else {
      __builtin_amdgcn_s_waitcnt(0x0F70);          // vmcnt(0)
    }
    __builtin_amdgcn_s_barrier();

    f16* Ks = Kb + (i & 1) * 4096;
    f16* Vt = Vb + (i & 1) * 4096;

    // two independent 32-key halves: QK^T -> softmax -> PV each
#pragma unroll
    for (int hk = 0; hk < 2; ++hk) {
      // QK^T: st[key-subtile][q-group], C layout col=c(query), row=q*4+r(key)
      f32x4 st[2][4] = {};
#pragma unroll
      for (int kh = 0; kh < 2; ++kh) {
        f16x8 kf[2];
#pragma unroll
        for (int mt = 0; mt < 2; ++mt)
          kf[mt] = *(const f16x8*)(Ks + ((hk * 2 + mt) * 16 + c) * 64 + ((kh * 4 + q) ^ cx) * 8);
        __builtin_amdgcn_s_setprio(1);
#pragma unroll
        for (int mt = 0; mt < 2; ++mt)
#pragma unroll
          for (int g = 0; g < 4; ++g)
            st[mt][g] = MFMA16(kf[mt], qf[g][kh], st[mt][g]);
        __builtin_amdgcn_s_setprio(0);
      }

      // softmax (exp2, cs folded into Q); P packed straight into A-fragments:
      // pf[g] element j: j<4 -> st[0][g][j], j>=4 -> st[1][g][j-4]
      f16x8 pf[4];
#pragma unroll
      for (int g = 0; g < 4; ++g) {
        float s = 0.f;
#pragma unroll
        for (int mt = 0; mt < 2; ++mt) {
          float p0 = __builtin_amdgcn_exp2f(st[mt][g][0]);
          float p1 = __builtin_amdgcn_exp2f(st[mt][g][1]);
          float p2 = __builtin_amdgcn_exp2f(st[mt][g][2]);
          float p3 = __builtin_amdgcn_exp2f(st[mt][g][3]);
          s += (p0 + p1) + (p2 + p3);
          int hh = mt * 4;
          pf[g][hh + 0] = (f16)p0; pf[g][hh + 1] = (f16)p1;
          pf[g][hh + 2] = (f16)p2; pf[g][hh + 3] = (f16)p3;
        }
        l_[g] += s;  // lane-partial; cross-q reduce deferred to epilogue
      }

      // PV: each V fragment read once, feeds all 4 q-groups
      __builtin_amdgcn_s_setprio(1);
#pragma unroll
      for (int d = 0; d < 4; ++d) {
        f16x8 vf = *(const f16x8*)(Vt + (d * 16 + c) * 64 + ((hk * 4 + q) ^ cx) * 8);
        o_[0][d] = MFMA16(pf[0], vf, o_[0][d]);
        o_[1][d] = MFMA16(pf[1], vf, o_[1][d]);
        o_[2][d] = MFMA16(pf[2], vf, o_[2][d]);
        o_[3][d] = MFMA16(pf[3], vf, o_[3][d]);
      }
      __builtin_amdgcn_s_setprio(0);
    }
    MEMBAR();  // LDS reads ordered before end barrier / next DMA refill
    __builtin_amdgcn_s_barrier();
  }

  // deferred softmax-denominator reduce (no online rescale in this kernel)
#pragma unroll
  for (int g = 0; g < 4; ++g) {
    l_[g] += __shfl_xor(l_[g], 16);
    l_[g] += __shfl_xor(l_[g], 32);
  }

#pragma unroll
  for (int g = 0; g < 4; ++g)
#pragma unroll
    for (int r = 0; r < 4; ++r) {
      float linv = 1.0f / __shfl(l_[g], q * 4 + r);
      size_t row = (size_t)qt * 256 + w * 64 + g * 16 + q * 4 + r;
#pragma unroll
      for (int d = 0; d < 4; ++d)
        Og[base + row * D + d * 16 + c] = (f16)(o_[g][d][r] * linv);
    }
}

// ---------------- launch ----------------
extern "C" void kernel_launch(void* const* d_in, const int* in_sizes, int n_in,
                              void* d_out, int out_size, void* d_ws, size_t ws_size,
                              hipStream_t stream) {
  const float* x  = (const float*)d_in[0];
  const float* Wq = (const float*)d_in[1];
  const float* Wk = (const float*)d_in[2];
  const float* Wv = (const float*)d_in[3];
  const float* Wo = (const float*)d_in[4];
  char* ws = (char*)d_ws;
  const size_t MB = 1ull << 20;
  f16* X16  = (f16*)(ws + 0 * MB);    // 16 MB
  f16* Wq16 = (f16*)(ws + 16 * MB);   // 2 MB each
  f16* Wk16 = (f16*)(ws + 18 * MB);
  f16* Wv16 = (f16*)(ws + 20 * MB);
  f16* Wo16 = (f16*)(ws + 22 * MB);
  f16* Q16  = (f16*)(ws + 24 * MB);   // 16 MB each
  f16* K16  = (f16*)(ws + 40 * MB);
  f16* VT16 = (f16*)(ws + 56 * MB);   // V^T: [1024 dims][8192 tokens], permuted
  f16* A16  = (f16*)(ws + 72 * MB);   // total 88 MB

  const float cs = 0.18033688011112042f;  // (1/sqrt(64)) * log2(e), folded into Q

  cvt_all<<<6144, 256, 0, stream>>>(x, Wq, Wk, Wv, Wo,
                                    X16, Wq16, Wk16, Wv16, Wo16);

  gemm_qkvt<<<dim3(512, 1, 3), 256, 0, stream>>>(
      X16, Wq16, Wk16, Wv16, Q16, K16, VT16, cs);

  attn_kernel<<<dim3(512, 1, 1), 256, 0, stream>>>(Q16, K16, VT16, A16);

  gemm_o<<<512, 256, 0, stream>>>(A16, Wo16, (float*)d_out);
}

// Round 5
// 254.633 us; speedup vs baseline: 1.0196x; 1.0196x over previous
//
#include <hip/hip_runtime.h>

typedef _Float16 f16;
typedef _Float16 f16x8 __attribute__((ext_vector_type(8)));
typedef _Float16 f16x4 __attribute__((ext_vector_type(4)));
typedef float f32x4 __attribute__((ext_vector_type(4)));

#define MFMA16(a, b, c) __builtin_amdgcn_mfma_f32_16x16x32_f16((a), (b), (c), 0, 0, 0)
// compiler-only fence: pins LDS op order across TBAA-distinct vector types
#define MEMBAR() __asm__ __volatile__("" ::: "memory")

// async global->LDS, 16B per lane. lds dest = wave-uniform base + lane*16.
__device__ __forceinline__ void cp16(const f16* g, f16* l) {
  __builtin_amdgcn_global_load_lds(
      (const __attribute__((address_space(1))) void*)g,
      (__attribute__((address_space(3))) void*)l, 16, 0, 0);
}

// ---------------- fp32 -> fp16 convert, all 5 tensors in one launch ----------------
__global__ __launch_bounds__(256) void cvt_all(
    const float* __restrict__ x,  const float* __restrict__ Wq,
    const float* __restrict__ Wk, const float* __restrict__ Wv,
    const float* __restrict__ Wo,
    f16* __restrict__ X16, f16* __restrict__ Wq16, f16* __restrict__ Wk16,
    f16* __restrict__ Wv16, f16* __restrict__ Wo16) {
  int blk = blockIdx.x;
  const float* src; f16* dst; size_t off;
  if (blk < 4096) { src = x; dst = X16; off = (size_t)blk * 2048; }
  else {
    int t = blk - 4096, widx = t >> 9, loc = t & 511;
    src = (widx == 0) ? Wq : (widx == 1) ? Wk : (widx == 2) ? Wv : Wo;
    dst = (widx == 0) ? Wq16 : (widx == 1) ? Wk16 : (widx == 2) ? Wv16 : Wo16;
    off = (size_t)loc * 2048;
  }
  size_t e = off + (size_t)threadIdx.x * 8;
  const float4* s = (const float4*)(src + e);
  float4 a = s[0], b = s[1];
  f16x8 o;
  o[0] = (f16)a.x; o[1] = (f16)a.y; o[2] = (f16)a.z; o[3] = (f16)a.w;
  o[4] = (f16)b.x; o[5] = (f16)b.y; o[6] = (f16)b.z; o[7] = (f16)b.w;
  *(f16x8*)(dst + e) = o;
}

// ---------------- pipelined GEMM core: C[M,N] = scale * A[M,K] * B[N,K]^T ----------------
// BM=BN=128, BK=32, double-buffered (32 KB LDS -> 4 blocks/CU). Per iter each
// wave prefetches tile i+1 (4 cp16, FIFO A0,A1,B0,B1), waits vmcnt(4) (tile i),
// raw s_barrier, 8 ds_read_b128 + 16 MFMA, barrier. BK=32 swizzle: logical
// chunk q of row r stored at position q^((r>>1)&3) -> 8 lanes/bank-group (min).
// permT: permute low-6 column bits [b5 b4 b3 b2 b1 b0]->[b5 b3 b2 b4 b1 b0]
// (bakes attn's PV k-axis permutation into the global VT layout).
__device__ __forceinline__ void gemm_core(
    const f16* __restrict__ A, const f16* __restrict__ B, void* __restrict__ Cv,
    bool outF16, bool permT, int N, int K, int bm, int bn, float scale,
    f16* As, f16* Bs) {
  const int tid = threadIdx.x;
  const int lane = tid & 63, w = tid >> 6;
  const int wm = w >> 1, wn = w & 1;
  const int c = lane & 15, q = lane >> 4;
  const int key = (c >> 1) & 3;  // read-side swizzle key
  f32x4 acc[4][4] = {};

  // stage one BK=32 tile into buffer bufi: per wave 2 windows x (A,B)
  const int Lrow = lane >> 2, Lp = (lane & 3) ^ ((lane >> 3) & 3);
  auto stage = [&](int k0, int bufi) {
#pragma unroll
    for (int j = 0; j < 2; ++j) {
      int r0 = (w * 2 + j) * 16;
      cp16(A + (size_t)(bm + r0 + Lrow) * K + k0 + Lp * 8,
           As + bufi * 4096 + r0 * 32 + lane * 8);
    }
#pragma unroll
    for (int j = 0; j < 2; ++j) {
      int r0 = (w * 2 + j) * 16;
      cp16(B + (size_t)(bn + r0 + Lrow) * K + k0 + Lp * 8,
           Bs + bufi * 4096 + r0 * 32 + lane * 8);
    }
  };

  stage(0, 0);
  const int NIT = K >> 5;
  for (int i = 0; i < NIT; ++i) {
    if (i + 1 < NIT) {
      stage((i + 1) << 5, (i + 1) & 1);     // prefetch, stays in flight
      __builtin_amdgcn_s_waitcnt(0x0F74);   // vmcnt(4): tile i's loads only
    } else {
      __builtin_amdgcn_s_waitcnt(0x0F70);   // vmcnt(0)
    }
    __builtin_amdgcn_s_barrier();
    MEMBAR();
    const f16* Ab = As + (i & 1) * 4096;
    const f16* Bb = Bs + (i & 1) * 4096;
    f16x8 af[4], bf[4];
#pragma unroll
    for (int mt = 0; mt < 4; ++mt)
      af[mt] = *(const f16x8*)(Ab + (wm * 64 + mt * 16 + c) * 32 + (q ^ key) * 8);
#pragma unroll
    for (int nt = 0; nt < 4; ++nt)
      bf[nt] = *(const f16x8*)(Bb + (wn * 64 + nt * 16 + c) * 32 + (q ^ key) * 8);
#pragma unroll
    for (int mt = 0; mt < 4; ++mt)
#pragma unroll
      for (int nt = 0; nt < 4; ++nt)
        acc[mt][nt] = MFMA16(af[mt], bf[nt], acc[mt][nt]);
    MEMBAR();
    __builtin_amdgcn_s_barrier();  // all waves done with buf i&1 before refill
  }

#pragma unroll
  for (int mt = 0; mt < 4; ++mt)
#pragma unroll
    for (int nt = 0; nt < 4; ++nt)
#pragma unroll
      for (int r = 0; r < 4; ++r) {
        size_t row = bm + wm * 64 + mt * 16 + q * 4 + r;  // C/D: row=(lane>>4)*4+reg
        size_t col = bn + wn * 64 + nt * 16 + c;          //      col=lane&15
        if (permT) {
          int t = (int)col & 63;
          col = (col & ~(size_t)63) |
                (size_t)((t & 0x23) | ((t & 0x0C) << 1) | ((t & 0x10) >> 2));
        }
        float v = acc[mt][nt][r] * scale;
        if (outF16) ((f16*)Cv)[row * N + col] = (f16)v;
        else ((float*)Cv)[row * N + col] = v;
      }
}

// fused Q/K/V^T projections: z=0 Q=X·Wq^T (scaled cs), z=1 K=X·Wk^T,
// z=2 V^T = Wv·X^T (M=1024, N=8192 -> dim-major, key-permuted for attn)
__global__ __launch_bounds__(256, 4) void gemm_qkvt(
    const f16* __restrict__ X, const f16* __restrict__ Wq,
    const f16* __restrict__ Wk, const f16* __restrict__ Wv,
    f16* __restrict__ Q, f16* __restrict__ Ko, f16* __restrict__ VT, float cs) {
  __shared__ __align__(16) f16 As[8192], Bs[8192];
  const int z = blockIdx.z, x = blockIdx.x;
  if (z < 2) {
    gemm_core(X, z ? Wk : Wq, z ? (void*)Ko : (void*)Q, true, false, 1024, 1024,
              (x >> 3) * 128, (x & 7) * 128, z ? 1.0f : cs, As, Bs);
  } else {
    gemm_core(Wv, X, (void*)VT, true, true, 8192, 1024,
              (x >> 6) * 128, (x & 63) * 128, 1.0f, As, Bs);
  }
}

// output projection: d_out(fp32) = A16 · Wo^T
__global__ __launch_bounds__(256, 4) void gemm_o(
    const f16* __restrict__ A, const f16* __restrict__ Wo, float* __restrict__ out) {
  __shared__ __align__(16) f16 As[8192], Bs[8192];
  const int x = blockIdx.x;
  gemm_core(A, Wo, (void*)out, false, false, 1024, 1024,
            (x >> 3) * 128, (x & 7) * 128, 1.0f, As, Bs);
}

// ---------------- flash attention (round-12: fused 64-key tile, 1 barrier/iter) ----------------
// 4-group/wave structure kept (round-11). Changes:
//  (1) full 64-key tile in one pass: all 32 QK MFMAs issue before any softmax
//      (st[4][4]=64 regs live) -> softmax runs under the MFMA cluster tail /
//      other wave's MFMAs; one 32-MFMA PV cluster.
//  (2) triple-buffered K/V (48 KB LDS) -> ONE s_barrier per iteration. Stage
//      is issued AFTER the entry barrier, targeting buf (i+2)%3 == the buffer
//      read at iter i-1, which the barrier just protected. vmcnt(4) entry.
//  (3) kf per-kh (4 regs) to cap peak VGPR ~200 (grid=2 blocks/CU exactly, so
//      regs are free up to 256; spill tripwire = WRITE_SIZE >> 16 MB).
__global__ __launch_bounds__(256, 2) void attn_kernel(
    const f16* __restrict__ Qg, const f16* __restrict__ Kg,
    const f16* __restrict__ VTg, f16* __restrict__ Og) {
  const int T = 2048, D = 1024;
  const int x = blockIdx.x;                 // 512 blocks flattened
  const int xcd = x & 7, rem = x >> 3;
  const int qt = rem & 7, grp = rem >> 3;
  const int bh = (grp << 3) | xcd;          // XCD = bh&7 for all 8 qt
  const int b = bh >> 4, h = bh & 15;
  const size_t base = ((size_t)b * T) * D + h * 64;            // Q, K, O
  const size_t baseV = (size_t)h * 64 * 8192 + (size_t)b * T;  // VT[1024][8192]
  __shared__ __align__(16) f16 smem[24576];  // 48 KB: K 3x8KB + V 3x8KB
  const int tid = threadIdx.x;
  const int lane = tid & 63, w = tid >> 6;   // w in [0,4)
  const int c = lane & 15, q = lane >> 4;
  const int cx = c & 7;
  f16* Kb = smem;                     // 3 bufs x [64*64] swizzled
  f16* Vb = smem + 12288;             // 3 bufs x [64*64] swizzled (keys pre-permuted)

  // stage Q: 256 rows x 64 dims into smem[0:16384) (overlaps KV bufs; staged
  // and consumed before the KV pipeline starts)
#pragma unroll
  for (int j = 0; j < 8; ++j) {
    int cb = (w * 8 + j) * 64;
    int ch = cb + lane;
    int row = ch >> 3, p = (ch & 7) ^ (row & 7);
    cp16(Qg + base + (size_t)(qt * 256 + row) * D + p * 8, smem + cb * 8);
  }
  __syncthreads();
  f16x8 qf[4][2];  // Q^T B-fragments, persistent (rows w*64 .. w*64+63)
#pragma unroll
  for (int g = 0; g < 4; ++g)
#pragma unroll
    for (int kh = 0; kh < 2; ++kh)
      qf[g][kh] = *(const f16x8*)(smem + (w * 64 + g * 16 + c) * 64 + ((kh * 4 + q) ^ cx) * 8);
  __syncthreads();  // all qf reads done before DMA overwrites Q region

  float l_[4] = {0.f, 0.f, 0.f, 0.f};
  f32x4 o_[4][4] = {};

  // per wave: 2 K cp16 + 2 V cp16 cover one 64x64 K tile + V tile across 4 waves
  auto stageKV = [&](int kv, int bufi) {
    f16* Ks = Kb + bufi * 4096;
    f16* Vt = Vb + bufi * 4096;
#pragma unroll
    for (int j = 0; j < 2; ++j) {
      int cb = (w * 2 + j) * 64;
      int ch = cb + lane;
      int row = ch >> 3, p = (ch & 7) ^ (row & 7);
      cp16(Kg + base + (size_t)(kv + row) * D + p * 8, Ks + cb * 8);
    }
#pragma unroll
    for (int j = 0; j < 2; ++j) {
      int cb = (w * 2 + j) * 64;
      int ch = cb + lane;
      int row = ch >> 3, p = (ch & 7) ^ (row & 7);
      cp16(VTg + baseV + (size_t)row * 8192 + kv + p * 8, Vt + cb * 8);
    }
  };

  stageKV(0, 0);
  stageKV(64, 1);
  for (int i = 0; i < 32; ++i) {
    if (i < 31) __builtin_amdgcn_s_waitcnt(0x0F74);  // vmcnt(4): tile i ready
    else        __builtin_amdgcn_s_waitcnt(0x0F70);  // vmcnt(0)
    __builtin_amdgcn_s_barrier();   // tile i visible to all; iter i-1 reads done
    MEMBAR();
    if (i + 2 < 32) stageKV((i + 2) * 64, (i + 2) % 3);  // overwrites buf read at i-1

    const f16* Ks = Kb + (i % 3) * 4096;
    const f16* Vt = Vb + (i % 3) * 4096;

    // QK^T, full 64-key tile: st[key-subtile][q-group]
    // C layout col=c(query), row=q*4+r(key)
    f32x4 st[4][4] = {};
#pragma unroll
    for (int kh = 0; kh < 2; ++kh) {
      f16x8 kf[4];
#pragma unroll
      for (int mt = 0; mt < 4; ++mt)
        kf[mt] = *(const f16x8*)(Ks + (mt * 16 + c) * 64 + ((kh * 4 + q) ^ cx) * 8);
      __builtin_amdgcn_s_setprio(1);
#pragma unroll
      for (int mt = 0; mt < 4; ++mt)
#pragma unroll
        for (int g = 0; g < 4; ++g)
          st[mt][g] = MFMA16(kf[mt], qf[g][kh], st[mt][g]);
      __builtin_amdgcn_s_setprio(0);
    }

    // softmax (exp2, cs folded into Q); P packed straight into A-fragments:
    // pf[g][kc] element j: j<4 -> st[2kc][g][j], j>=4 -> st[2kc+1][g][j-4]
    f16x8 pf[4][2];
#pragma unroll
    for (int g = 0; g < 4; ++g) {
      float s = 0.f;
#pragma unroll
      for (int mt = 0; mt < 4; ++mt) {
        float p0 = __builtin_amdgcn_exp2f(st[mt][g][0]);
        float p1 = __builtin_amdgcn_exp2f(st[mt][g][1]);
        float p2 = __builtin_amdgcn_exp2f(st[mt][g][2]);
        float p3 = __builtin_amdgcn_exp2f(st[mt][g][3]);
        s += (p0 + p1) + (p2 + p3);
        int kc = mt >> 1, hh = (mt & 1) * 4;
        pf[g][kc][hh + 0] = (f16)p0; pf[g][kc][hh + 1] = (f16)p1;
        pf[g][kc][hh + 2] = (f16)p2; pf[g][kc][hh + 3] = (f16)p3;
      }
      l_[g] += s;  // lane-partial; cross-q reduce deferred to epilogue
    }

    // single PV cluster: each V fragment read once, feeds all 4 q-groups
    __builtin_amdgcn_s_setprio(1);
#pragma unroll
    for (int kc = 0; kc < 2; ++kc)
#pragma unroll
      for (int d = 0; d < 4; ++d) {
        f16x8 vf = *(const f16x8*)(Vt + (d * 16 + c) * 64 + ((kc * 4 + q) ^ cx) * 8);
        o_[0][d] = MFMA16(pf[0][kc], vf, o_[0][d]);
        o_[1][d] = MFMA16(pf[1][kc], vf, o_[1][d]);
        o_[2][d] = MFMA16(pf[2][kc], vf, o_[2][d]);
        o_[3][d] = MFMA16(pf[3][kc], vf, o_[3][d]);
      }
    __builtin_amdgcn_s_setprio(0);
    MEMBAR();  // LDS reads ordered before next iteration's barrier/DMA
  }

  // deferred softmax-denominator reduce (no online rescale in this kernel)
#pragma unroll
  for (int g = 0; g < 4; ++g) {
    l_[g] += __shfl_xor(l_[g], 16);
    l_[g] += __shfl_xor(l_[g], 32);
  }

#pragma unroll
  for (int g = 0; g < 4; ++g)
#pragma unroll
    for (int r = 0; r < 4; ++r) {
      float linv = 1.0f / __shfl(l_[g], q * 4 + r);
      size_t row = (size_t)qt * 256 + w * 64 + g * 16 + q * 4 + r;
#pragma unroll
      for (int d = 0; d < 4; ++d)
        Og[base + row * D + d * 16 + c] = (f16)(o_[g][d][r] * linv);
    }
}

// ---------------- launch ----------------
extern "C" void kernel_launch(void* const* d_in, const int* in_sizes, int n_in,
                              void* d_out, int out_size, void* d_ws, size_t ws_size,
                              hipStream_t stream) {
  const float* x  = (const float*)d_in[0];
  const float* Wq = (const float*)d_in[1];
  const float* Wk = (const float*)d_in[2];
  const float* Wv = (const float*)d_in[3];
  const float* Wo = (const float*)d_in[4];
  char* ws = (char*)d_ws;
  const size_t MB = 1ull << 20;
  f16* X16  = (f16*)(ws + 0 * MB);    // 16 MB
  f16* Wq16 = (f16*)(ws + 16 * MB);   // 2 MB each
  f16* Wk16 = (f16*)(ws + 18 * MB);
  f16* Wv16 = (f16*)(ws + 20 * MB);
  f16* Wo16 = (f16*)(ws + 22 * MB);
  f16* Q16  = (f16*)(ws + 24 * MB);   // 16 MB each
  f16* K16  = (f16*)(ws + 40 * MB);
  f16* VT16 = (f16*)(ws + 56 * MB);   // V^T: [1024 dims][8192 tokens], permuted
  f16* A16  = (f16*)(ws + 72 * MB);   // total 88 MB

  const float cs = 0.18033688011112042f;  // (1/sqrt(64)) * log2(e), folded into Q

  cvt_all<<<6144, 256, 0, stream>>>(x, Wq, Wk, Wv, Wo,
                                    X16, Wq16, Wk16, Wv16, Wo16);

  gemm_qkvt<<<dim3(512, 1, 3), 256, 0, stream>>>(
      X16, Wq16, Wk16, Wv16, Q16, K16, VT16, cs);

  attn_kernel<<<dim3(512, 1, 1), 256, 0, stream>>>(Q16, K16, VT16, A16);

  gemm_o<<<512, 256, 0, stream>>>(A16, Wo16, (float*)d_out);
}